// Round 6
// baseline (1442.836 us; speedup 1.0000x reference)
//
#include <hip/hip_runtime.h>

#define HID 128
#define ODIM 64

typedef _Float16 half8 __attribute__((ext_vector_type(8)));
typedef float f32x4 __attribute__((ext_vector_type(4)));

typedef const __attribute__((address_space(1))) void* as1cvp;
typedef __attribute__((address_space(3))) void* as3vp;

// async global->LDS, 16B per lane, dest = wave-uniform base + lane*16 (HW rule)
__device__ __forceinline__ void gload16(const void* g, void* l) {
  __builtin_amdgcn_global_load_lds((as1cvp)g, (as3vp)l, 16, 0, 0);
}

// ---------------------------------------------------------------------------
// k_prep (v6's, numerically proven): split weights to f16 hi/lo planes,
// transposed [n][k], K-chunked, unpadded stride 32 halves (64B rows -- these
// are now read from GLOBAL, where contiguity is what matters, not banks).
//   WspHi: [L=4][kc=4][n=128][32]   offset 0       (65536)
//   WspLo: [L=4][kc=4][n=128][32]   offset 65536   (65536)
//   WhHi : [kc=4][n=64][32]         offset 131072  ( 8192)
//   WhLo : [kc=4][n=64][32]         offset 139264  ( 8192)
// ---------------------------------------------------------------------------
__global__ __launch_bounds__(256) void k_prep(
    const float* __restrict__ Wg, const float* __restrict__ Wout,
    _Float16* __restrict__ WspHi, _Float16* __restrict__ WspLo,
    _Float16* __restrict__ WhHi, _Float16* __restrict__ WhLo) {
  int i = blockIdx.x * 256 + threadIdx.x;
  if (i < 65536) {  // hidden hi
    int kp = i & 31, n = (i >> 5) & 127, kc = (i >> 12) & 3, l = i >> 14;
    float v = Wg[(size_t)(l * 128 + kc * 32 + kp) * 128 + n];
    WspHi[i] = (_Float16)v;
  } else if (i < 131072) {  // hidden lo
    int j = i - 65536;
    int kp = j & 31, n = (j >> 5) & 127, kc = (j >> 12) & 3, l = j >> 14;
    float v = Wg[(size_t)(l * 128 + kc * 32 + kp) * 128 + n];
    _Float16 h = (_Float16)v;
    WspLo[j] = (_Float16)(v - (float)h);
  } else if (i < 139264) {  // head hi
    int j = i - 131072;
    int kp = j & 31, n = (j >> 5) & 63, kc = j >> 11;
    float v = Wout[(kc * 32 + kp) * 64 + n];
    WhHi[j] = (_Float16)v;
  } else if (i < 147456) {  // head lo
    int j = i - 139264;
    int kp = j & 31, n = (j >> 5) & 63, kc = j >> 11;
    float v = Wout[(kc * 32 + kp) * 64 + n];
    _Float16 h = (_Float16)v;
    WhLo[j] = (_Float16)(v - (float)h);
  }
}

// ---------------------------------------------------------------------------
// Encode (v3's, proven)
// ---------------------------------------------------------------------------
__global__ __launch_bounds__(256) void k_encode(
    const int* __restrict__ grids, const float* __restrict__ Win,
    const float* __restrict__ binp, float* __restrict__ X, int b0, int nodes) {
  int t = blockIdx.x * 256 + threadIdx.x;
  if (t >= nodes * 32) return;
  int node = t >> 5;
  int i = t & 31;
  int n = node % 900;
  int b = node / 900;
  int r = n / 30, c = n - r * 30;
  int color = grids[(b0 + b) * 900 + n];
  float fr = (float)r / 29.0f, fc = (float)c / 29.0f;
  f32x4 wc = ((const f32x4*)(Win + color * HID))[i];
  f32x4 wr = ((const f32x4*)(Win + 10 * HID))[i];
  f32x4 wl = ((const f32x4*)(Win + 11 * HID))[i];
  f32x4 bb = ((const f32x4*)binp)[i];
  f32x4 v = wc + fr * wr + fc * wl + bb;
#pragma unroll
  for (int j = 0; j < 4; ++j) v[j] = fmaxf(v[j], 0.0f);
  ((f32x4*)(X + (size_t)node * HID))[i] = v;
}

// ---------------------------------------------------------------------------
// Fused GCN layer v7: Xout = relu(LN((A·X)@W + bg)) + X
//
// T3 2-phase double-buffered pipeline (the structure v3 lacked):
//   prologue: STAGE(buf0, kc=0); barrier
//   loop kc : STAGE(buf^1, kc+1)   <- issued BEFORE compute
//             compute(buf[cur])     <- ds_read stencil + B-from-global + MFMA
//             barrier (vmcnt drain is now ~free: loads had a full phase)
//  - STAGE via global_load_lds: zero staging VGPRs (v4's spill fix) with
//    v5's numerically-verified granule XOR swizzle (linear dest, pre-swizzled
//    source, swizzled read; balanced b128: each bank-quad serves 8 lanes).
//  - W in LDS eliminated: B fragments read direct from global pre-split
//    planes. Wave pattern = 16 consecutive rows x 64B = 1KB contiguous per
//    instruction (ideal coalescing); 256KB total -> L2-resident. This frees
//    LDS for the X double-buffer: 2 x 320 x 32 f32 = 81920 B = 2 blocks/CU.
//  - v6's bijective XCD swizzle kept (halo L2 locality).
// Numerics bit-identical to v3 (same clamps, FMA order, split, epilogue).
// ---------------------------------------------------------------------------
__global__ __launch_bounds__(512, 4) void k_hidden(
    const float* __restrict__ Xin, float* __restrict__ Xout,
    const _Float16* __restrict__ Whi, const _Float16* __restrict__ Wlo,
    const float* __restrict__ bgp, const float* __restrict__ gamp,
    const float* __restrict__ betp, int nodesTotal) {
  // [2 buffers][320 rows][32 dwords]; row r slot v holds global granule v^(r&7)
  __shared__ __attribute__((aligned(16))) float Xt[2][320 * 32];  // 81920 B

  const int t = threadIdx.x;
  const int lane = t & 63;
  const int wave = t >> 6;
  const int q = lane >> 4, l16 = lane & 15;

  // bijective XCD-chunked swizzle (nwg=1800 -> 225 consecutive tiles per XCD)
  int nwg = gridDim.x, bid = blockIdx.x;
  int qd = nwg >> 3, rm = nwg & 7;
  int xcd = bid & 7, idx = bid >> 3;
  int wg = (xcd < rm ? xcd * (qd + 1) : rm * (qd + 1) + (xcd - rm) * qd) + idx;
  const int blockRow0 = wg * 256;
  const int waveRow0 = blockRow0 + wave * 32;

  // Stencil offsets (within one buffer) + symmetric-norm weights.
  // off = LDS dword offset of global granule 2q of neighbor row; granule
  // 2q+1 sits at off^4. Invalid directions carry weight 0.
  int off[2][5];
  float wts[2][5];
#pragma unroll
  for (int mt = 0; mt < 2; ++mt) {
    int nd = waveRow0 + mt * 16 + l16;
    if (nd > nodesTotal - 1) nd = nodesTotal - 1;
    int n = nd % 900;
    int r = n / 30, c = n - r * 30;
    int loc = nd - blockRow0 + 30;  // in [30, 285]
    int nb[5] = {loc, loc - 30, loc + 30, loc - 1, loc + 1};
    float dc = rsqrtf((float)(1 + (r > 0) + (r < 29) + (c > 0) + (c < 29)));
    wts[mt][0] = dc * dc;
    wts[mt][1] = (r > 0) ? dc * rsqrtf((float)(2 + (r > 1) + (c > 0) + (c < 29))) : 0.f;
    wts[mt][2] = (r < 29) ? dc * rsqrtf((float)(2 + (r < 28) + (c > 0) + (c < 29))) : 0.f;
    wts[mt][3] = (c > 0) ? dc * rsqrtf((float)(2 + (r > 0) + (r < 29) + (c > 1))) : 0.f;
    wts[mt][4] = (c < 29) ? dc * rsqrtf((float)(2 + (r > 0) + (r < 29) + (c < 28))) : 0.f;
#pragma unroll
    for (int e = 0; e < 5; ++e)
      off[mt][e] = nb[e] * 32 + (((2 * q) ^ (nb[e] & 7)) << 2);
  }

  // async stage of K-chunk kc into buffer buf (5 gload16/thread, 0 VGPRs)
  auto stage = [&](int kc, int buf) {
#pragma unroll
    for (int s = 0; s < 5; ++s) {
      int f = t + s * 512;
      int row = f >> 3, v = f & 7;
      int gr = blockRow0 - 30 + row;
      gr = gr < 0 ? 0 : (gr > nodesTotal - 1 ? nodesTotal - 1 : gr);
      gload16(Xin + (size_t)gr * HID + kc * 32 + ((v ^ (row & 7)) << 2),
              &Xt[buf][(s * 512 + wave * 64) << 2]);
    }
  };

  f32x4 acc[2][8];
#pragma unroll
  for (int mt = 0; mt < 2; ++mt)
#pragma unroll
    for (int nt = 0; nt < 8; ++nt) acc[mt][nt] = (f32x4){0.f, 0.f, 0.f, 0.f};

  stage(0, 0);
  __syncthreads();  // buf0 landed

  for (int kc = 0; kc < 4; ++kc) {
    const int cur = kc & 1;
    if (kc < 3) stage(kc + 1, cur ^ 1);  // issue early; lands during compute

    // ---- A fragments: 5-point stencil from LDS buffer, split f16 hi/lo
    const float* Xb = Xt[cur];
    half8 Ahi[2], Alo[2];
#pragma unroll
    for (int mt = 0; mt < 2; ++mt) {
      f32x4 s0 = {0.f, 0.f, 0.f, 0.f}, s1 = {0.f, 0.f, 0.f, 0.f};
#pragma unroll
      for (int e = 0; e < 5; ++e) {
        s0 += wts[mt][e] * (*(const f32x4*)(Xb + off[mt][e]));
        s1 += wts[mt][e] * (*(const f32x4*)(Xb + (off[mt][e] ^ 4)));
      }
#pragma unroll
      for (int j = 0; j < 4; ++j) {
        _Float16 h0 = (_Float16)s0[j];
        Ahi[mt][j] = h0;
        Alo[mt][j] = (_Float16)(s0[j] - (float)h0);
        _Float16 h1 = (_Float16)s1[j];
        Ahi[mt][4 + j] = h1;
        Alo[mt][4 + j] = (_Float16)(s1[j] - (float)h1);
      }
    }
    // ---- B fragments direct from global (1KB contiguous per wave-load,
    // L2-resident) + MFMA
    const int kb = q * 8;
    const _Float16* Wh = Whi + kc * 4096;
    const _Float16* Wl = Wlo + kc * 4096;
#pragma unroll
    for (int nt = 0; nt < 8; ++nt) {
      int n = nt * 16 + l16;
      half8 bhi = *(const half8*)(Wh + n * 32 + kb);
      half8 blo = *(const half8*)(Wl + n * 32 + kb);
#pragma unroll
      for (int mt = 0; mt < 2; ++mt) {
        acc[mt][nt] = __builtin_amdgcn_mfma_f32_16x16x32_f16(Alo[mt], bhi, acc[mt][nt], 0, 0, 0);
        acc[mt][nt] = __builtin_amdgcn_mfma_f32_16x16x32_f16(Ahi[mt], blo, acc[mt][nt], 0, 0, 0);
        acc[mt][nt] = __builtin_amdgcn_mfma_f32_16x16x32_f16(Ahi[mt], bhi, acc[mt][nt], 0, 0, 0);
      }
    }
    __syncthreads();  // reads of buf[cur] done; staged loads drained
  }

  // ---- epilogue: bias + LN + relu + residual, direct store from C/D layout
  float bgv[8], gv[8], btv[8];
#pragma unroll
  for (int nt = 0; nt < 8; ++nt) {
    int cl = nt * 16 + l16;
    bgv[nt] = bgp[cl];
    gv[nt] = gamp[cl];
    btv[nt] = betp[cl];
  }
#pragma unroll
  for (int mt = 0; mt < 2; ++mt) {
#pragma unroll
    for (int reg = 0; reg < 4; ++reg) {
      float rs = 0.f;
#pragma unroll
      for (int nt = 0; nt < 8; ++nt) {
        acc[mt][nt][reg] += bgv[nt];
        rs += acc[mt][nt][reg];
      }
      rs += __shfl_xor(rs, 1, 64);
      rs += __shfl_xor(rs, 2, 64);
      rs += __shfl_xor(rs, 4, 64);
      rs += __shfl_xor(rs, 8, 64);
      float mean = rs * (1.f / 128.f);
      float ss = 0.f;
#pragma unroll
      for (int nt = 0; nt < 8; ++nt) {
        float d = acc[mt][nt][reg] - mean;
        ss += d * d;
      }
      ss += __shfl_xor(ss, 1, 64);
      ss += __shfl_xor(ss, 2, 64);
      ss += __shfl_xor(ss, 4, 64);
      ss += __shfl_xor(ss, 8, 64);
      float rsd = rsqrtf(ss * (1.f / 128.f) + 1e-5f);
      int row = waveRow0 + mt * 16 + q * 4 + reg;  // uniform across the 16-lane group
      if (row < nodesTotal) {
        const float* xr = Xin + (size_t)row * HID;
        float* xo = Xout + (size_t)row * HID;
#pragma unroll
        for (int nt = 0; nt < 8; ++nt) {
          int col = nt * 16 + l16;
          float y = fmaxf((acc[mt][nt][reg] - mean) * rsd * gv[nt] + btv[nt], 0.f);
          xo[col] = y + xr[col];
        }
      }
    }
  }
}

// ---------------------------------------------------------------------------
// Head v7: Out = Xin @ Wout + bout. Same 2-phase dbuf pipeline, B from global.
// ---------------------------------------------------------------------------
__global__ __launch_bounds__(512, 4) void k_head(
    const float* __restrict__ Xin, float* __restrict__ Out,
    const _Float16* __restrict__ Whi, const _Float16* __restrict__ Wlo,
    const float* __restrict__ bp, int nodesTotal) {
  __shared__ __attribute__((aligned(16))) float Xt[2][256 * 32];  // 65536 B

  const int t = threadIdx.x;
  const int lane = t & 63;
  const int wave = t >> 6;
  const int q = lane >> 4, l16 = lane & 15;
  const int blockRow0 = blockIdx.x * 256;
  const int waveRow0 = blockRow0 + wave * 32;

  int off[2];
#pragma unroll
  for (int mt = 0; mt < 2; ++mt) {
    int nd = waveRow0 + mt * 16 + l16;
    if (nd > nodesTotal - 1) nd = nodesTotal - 1;
    int rn = nd - blockRow0;
    off[mt] = rn * 32 + (((2 * q) ^ (rn & 7)) << 2);
  }

  auto stage = [&](int kc, int buf) {
#pragma unroll
    for (int s = 0; s < 4; ++s) {  // 2048 granules = 4*512 exactly
      int f = t + s * 512;
      int row = f >> 3, v = f & 7;
      int gr = blockRow0 + row;
      if (gr > nodesTotal - 1) gr = nodesTotal - 1;
      gload16(Xin + (size_t)gr * HID + kc * 32 + ((v ^ (row & 7)) << 2),
              &Xt[buf][(s * 512 + wave * 64) << 2]);
    }
  };

  f32x4 acc[2][4];
#pragma unroll
  for (int mt = 0; mt < 2; ++mt)
#pragma unroll
    for (int nt = 0; nt < 4; ++nt) acc[mt][nt] = (f32x4){0.f, 0.f, 0.f, 0.f};

  stage(0, 0);
  __syncthreads();

  for (int kc = 0; kc < 4; ++kc) {
    const int cur = kc & 1;
    if (kc < 3) stage(kc + 1, cur ^ 1);

    const float* Xb = Xt[cur];
    half8 Ahi[2], Alo[2];
#pragma unroll
    for (int mt = 0; mt < 2; ++mt) {
      f32x4 s0 = *(const f32x4*)(Xb + off[mt]);
      f32x4 s1 = *(const f32x4*)(Xb + (off[mt] ^ 4));
#pragma unroll
      for (int j = 0; j < 4; ++j) {
        _Float16 h0 = (_Float16)s0[j];
        Ahi[mt][j] = h0;
        Alo[mt][j] = (_Float16)(s0[j] - (float)h0);
        _Float16 h1 = (_Float16)s1[j];
        Ahi[mt][4 + j] = h1;
        Alo[mt][4 + j] = (_Float16)(s1[j] - (float)h1);
      }
    }
    const int kb = q * 8;
    const _Float16* Wh = Whi + kc * 2048;
    const _Float16* Wl = Wlo + kc * 2048;
#pragma unroll
    for (int nt = 0; nt < 4; ++nt) {
      int n = nt * 16 + l16;
      half8 bhi = *(const half8*)(Wh + n * 32 + kb);
      half8 blo = *(const half8*)(Wl + n * 32 + kb);
#pragma unroll
      for (int mt = 0; mt < 2; ++mt) {
        acc[mt][nt] = __builtin_amdgcn_mfma_f32_16x16x32_f16(Alo[mt], bhi, acc[mt][nt], 0, 0, 0);
        acc[mt][nt] = __builtin_amdgcn_mfma_f32_16x16x32_f16(Ahi[mt], blo, acc[mt][nt], 0, 0, 0);
        acc[mt][nt] = __builtin_amdgcn_mfma_f32_16x16x32_f16(Ahi[mt], bhi, acc[mt][nt], 0, 0, 0);
      }
    }
    __syncthreads();
  }

  float bv[4];
#pragma unroll
  for (int nt = 0; nt < 4; ++nt) bv[nt] = bp[nt * 16 + l16];
#pragma unroll
  for (int mt = 0; mt < 2; ++mt) {
#pragma unroll
    for (int reg = 0; reg < 4; ++reg) {
      int row = waveRow0 + mt * 16 + q * 4 + reg;
      if (row < nodesTotal) {
        float* op = Out + (size_t)row * ODIM;
#pragma unroll
        for (int nt = 0; nt < 4; ++nt)
          op[nt * 16 + l16] = acc[mt][nt][reg] + bv[nt];
      }
    }
  }
}

// ---------------------------------------------------------------------------
extern "C" void kernel_launch(void* const* d_in, const int* in_sizes, int n_in,
                              void* d_out, int out_size, void* d_ws, size_t ws_size,
                              hipStream_t stream) {
  const int* grids = (const int*)d_in[0];
  // d_in[1] = edge_index: unused (fixed 30x30 grid + self-loops, analytic coefs)
  const float* Win  = (const float*)d_in[2];
  const float* bin  = (const float*)d_in[3];
  const float* Wg   = (const float*)d_in[4];
  const float* bg   = (const float*)d_in[5];
  const float* gam  = (const float*)d_in[6];
  const float* bet  = (const float*)d_in[7];
  const float* Wout = (const float*)d_in[8];
  const float* bout = (const float*)d_in[9];
  float* Out = (float*)d_out;

  // workspace: [pre-split W (294912 B) | Xa | Xb]
  _Float16* WspHi = (_Float16*)d_ws;
  _Float16* WspLo = WspHi + 65536;
  _Float16* WhHi  = WspHi + 131072;
  _Float16* WhLo  = WspHi + 139264;
  const size_t wBytes = 294912;

  const int Btot = 512;
  const size_t perBatchBytes = (size_t)900 * HID * 4 * 2;  // ping-pong X buffers
  size_t xws = ws_size > wBytes ? ws_size - wBytes : 0;
  int chunkB = (int)(xws / perBatchBytes);
  if (chunkB > Btot) chunkB = Btot;
  if (chunkB < 1) chunkB = 1;
  int nch = (Btot + chunkB - 1) / chunkB;

  float* Xa = (float*)((char*)d_ws + wBytes);
  float* Xb = Xa + (size_t)chunkB * 900 * HID;

  k_prep<<<dim3(576), dim3(256), 0, stream>>>(Wg, Wout, WspHi, WspLo, WhHi, WhLo);

  for (int ci = 0; ci < nch; ++ci) {
    int b0 = ci * chunkB;
    int cb = Btot - b0;
    if (cb > chunkB) cb = chunkB;
    int nodes = cb * 900;
    int gb = (nodes + 255) / 256;

    k_encode<<<dim3((nodes * 32 + 255) / 256), dim3(256), 0, stream>>>(
        grids, Win, bin, Xa, b0, nodes);
    float* src = Xa;
    float* dst = Xb;
    for (int l = 0; l < 4; ++l) {
      k_hidden<<<dim3(gb), dim3(512), 0, stream>>>(
          src, dst, WspHi + l * 16384, WspLo + l * 16384,
          bg + l * HID, gam + l * HID, bet + l * HID, nodes);
      float* tmp = src; src = dst; dst = tmp;
    }
    // after 4 swaps the final X is back in Xa
    k_head<<<dim3(gb), dim3(512), 0, stream>>>(
        src, Out + (size_t)b0 * 900 * ODIM, WhHi, WhLo, bout, nodes);
  }
}

// Round 7
// 1182.863 us; speedup vs baseline: 1.2198x; 1.2198x over previous
//
#include <hip/hip_runtime.h>

#define HID 128
#define ODIM 64

typedef _Float16 half8 __attribute__((ext_vector_type(8)));
typedef float f32x4 __attribute__((ext_vector_type(4)));

// ---------------------------------------------------------------------------
// k_prep: split all GEMM weights into f16 hi/lo planes ONCE, transposed to
// [n][k], K-chunked, rows padded to stride 40 halves (conflict-free b128).
// Layouts (in halves):
//   WspHi: [L=4][kc=4][n=128][40]   offset 0       (81920)
//   WspLo: [L=4][kc=4][n=128][40]   offset 81920   (81920)
//   WhHi : [kc=4][n=64][40]         offset 163840  (10240)
//   WhLo : [kc=4][n=64][40]         offset 174080  (10240)
// (verified rounds 3-6)
// ---------------------------------------------------------------------------
__global__ __launch_bounds__(256) void k_prep(
    const float* __restrict__ Wg, const float* __restrict__ Wout,
    _Float16* __restrict__ WspHi, _Float16* __restrict__ WspLo,
    _Float16* __restrict__ WhHi, _Float16* __restrict__ WhLo) {
  int i = blockIdx.x * 256 + threadIdx.x;
  if (i < 81920) {  // hidden hi
    int kp = i % 40, n = (i / 40) & 127, kc = (i / 5120) & 3, l = i / 20480;
    float v = kp < 32 ? Wg[(size_t)(l * 128 + kc * 32 + kp) * 128 + n] : 0.f;
    WspHi[i] = (_Float16)v;
  } else if (i < 163840) {  // hidden lo
    int j = i - 81920;
    int kp = j % 40, n = (j / 40) & 127, kc = (j / 5120) & 3, l = j / 20480;
    float v = kp < 32 ? Wg[(size_t)(l * 128 + kc * 32 + kp) * 128 + n] : 0.f;
    _Float16 h = (_Float16)v;
    WspLo[j] = (_Float16)(v - (float)h);
  } else if (i < 174080) {  // head hi
    int j = i - 163840;
    int kp = j % 40, n = (j / 40) & 63, kc = j / 2560;
    float v = kp < 32 ? Wout[(kc * 32 + kp) * 64 + n] : 0.f;
    WhHi[j] = (_Float16)v;
  } else if (i < 184320) {  // head lo
    int j = i - 174080;
    int kp = j % 40, n = (j / 40) & 63, kc = j / 2560;
    float v = kp < 32 ? Wout[(kc * 32 + kp) * 64 + n] : 0.f;
    _Float16 h = (_Float16)v;
    WhLo[j] = (_Float16)(v - (float)h);
  }
}

// ---------------------------------------------------------------------------
// Encode (v3's, verified)
// ---------------------------------------------------------------------------
__global__ __launch_bounds__(256) void k_encode(
    const int* __restrict__ grids, const float* __restrict__ Win,
    const float* __restrict__ binp, float* __restrict__ X, int b0, int nodes) {
  int t = blockIdx.x * 256 + threadIdx.x;
  if (t >= nodes * 32) return;
  int node = t >> 5;
  int i = t & 31;
  int n = node % 900;
  int b = node / 900;
  int r = n / 30, c = n - r * 30;
  int color = grids[(b0 + b) * 900 + n];
  float fr = (float)r / 29.0f, fc = (float)c / 29.0f;
  f32x4 wc = ((const f32x4*)(Win + color * HID))[i];
  f32x4 wr = ((const f32x4*)(Win + 10 * HID))[i];
  f32x4 wl = ((const f32x4*)(Win + 11 * HID))[i];
  f32x4 bb = ((const f32x4*)binp)[i];
  f32x4 v = wc + fr * wr + fc * wl + bb;
#pragma unroll
  for (int j = 0; j < 4; ++j) v[j] = fmaxf(v[j], 0.0f);
  ((f32x4*)(X + (size_t)node * HID))[i] = v;
}

// ---------------------------------------------------------------------------
// Fused GCN layer v8: Xout = relu(LN((A·X)@W + bg)) + X
//
// v3's verified structure (padded Xt, base+immediate stencil, sync staging),
// retiled for occupancy: wave = 16 rows x 128 cols (acc[8] = 32 regs instead
// of 64) -> fits 85-reg cap -> __launch_bounds__(512,6) -> 24 waves/CU
// (3 blocks x 8 waves), 1.5x the TLP of v3 to hide the staging-barrier
// latency. M=128 tile; LDS 27072(Xt 188x36) + 2x10240(W) = 47552 B
// (3 blocks = 142.8 KB <= 160 KB). Bijective XCD swizzle clusters
// neighboring tiles on one XCD so the larger M=128 halo re-reads hit L2.
// Numerics identical to v3 (same clamps, FMA order, split, epilogue).
// ---------------------------------------------------------------------------
__global__ __launch_bounds__(512, 6) void k_hidden(
    const float* __restrict__ Xin, float* __restrict__ Xout,
    const _Float16* __restrict__ Whi, const _Float16* __restrict__ Wlo,
    const float* __restrict__ bgp, const float* __restrict__ gamp,
    const float* __restrict__ betp, int nodesTotal) {
  constexpr int XTS = 36;    // Xt row stride in dwords (16B rows, 2-way alias = free)
  constexpr int XROWS = 188; // 128 + 2*30 halo
  __shared__ __attribute__((aligned(16))) float Xt[XROWS * XTS];    // 27072 B
  __shared__ __attribute__((aligned(16))) _Float16 WThi[128 * 40];  // 10240 B
  __shared__ __attribute__((aligned(16))) _Float16 WTlo[128 * 40];  // 10240 B

  const int t = threadIdx.x;
  const int lane = t & 63;
  const int wave = t >> 6;
  const int q = lane >> 4, l16 = lane & 15;

  // bijective XCD-chunked swizzle (verified v6/v7): consecutive wg -> same XCD
  int nwg = gridDim.x, bid = blockIdx.x;
  int qd = nwg >> 3, rm = nwg & 7;
  int xcd = bid & 7, idx = bid >> 3;
  int wg = (xcd < rm ? xcd * (qd + 1) : rm * (qd + 1) + (xcd - rm) * qd) + idx;
  const int blockRow0 = wg * 128;
  const int waveRow0 = blockRow0 + wave * 16;

  // Stencil: one LDS base (corner = up-neighbor row), neighbors via
  // compile-time dword offsets: up=0, left=1044, self=1080, right=1116,
  // down=2160. Invalid directions get weight 0 (staged data clamped-finite).
  int nd = waveRow0 + l16;
  if (nd > nodesTotal - 1) nd = nodesTotal - 1;
  int xb;
  float wts[5];
  {
    int n = nd % 900;
    int r = n / 30, c = n - r * 30;
    int loc = nd - blockRow0 + 30;  // in [30, 157]
    xb = (loc - 30) * XTS;
    float dc = rsqrtf((float)(1 + (r > 0) + (r < 29) + (c > 0) + (c < 29)));
    wts[0] = dc * dc;
    wts[1] = (r > 0) ? dc * rsqrtf((float)(2 + (r > 1) + (c > 0) + (c < 29))) : 0.f;
    wts[2] = (r < 29) ? dc * rsqrtf((float)(2 + (r < 28) + (c > 0) + (c < 29))) : 0.f;
    wts[3] = (c > 0) ? dc * rsqrtf((float)(2 + (r > 0) + (r < 29) + (c > 1))) : 0.f;
    wts[4] = (c < 29) ? dc * rsqrtf((float)(2 + (r > 0) + (r < 29) + (c < 28))) : 0.f;
  }

  f32x4 acc[8];
#pragma unroll
  for (int nt = 0; nt < 8; ++nt) acc[nt] = (f32x4){0.f, 0.f, 0.f, 0.f};

  for (int kc = 0; kc < 4; ++kc) {
    __syncthreads();  // previous iteration's LDS fully consumed
    // ---- stage X tile (coalesced f32x4), rows clamped into [0, nodesTotal)
    for (int f = t; f < XROWS * 8; f += 512) {
      int row = f >> 3, v = f & 7;
      int gr = blockRow0 - 30 + row;
      gr = gr < 0 ? 0 : (gr > nodesTotal - 1 ? nodesTotal - 1 : gr);
      *(f32x4*)(Xt + row * XTS + v * 4) =
          *(const f32x4*)(Xin + (size_t)gr * HID + kc * 32 + v * 4);
    }
    // ---- stage W K-chunk: pure linear copies from pre-split planes (L2-hot)
    {
      const f32x4* hs = (const f32x4*)(Whi + kc * 5120);
      for (int f = t; f < 640; f += 512) ((f32x4*)WThi)[f] = hs[f];
      const f32x4* ls = (const f32x4*)(Wlo + kc * 5120);
      for (int f = t; f < 640; f += 512) ((f32x4*)WTlo)[f] = ls[f];
    }
    __syncthreads();

    // ---- A fragment: 5-point stencil from LDS, split f16 hi/lo
    half8 Ahi, Alo;
    {
      const float* x0 = Xt + xb + q * 8;
      f32x4 s0 = wts[0] * (*(const f32x4*)(x0 + 1080));
      f32x4 s1 = wts[0] * (*(const f32x4*)(x0 + 1084));
      s0 += wts[1] * (*(const f32x4*)(x0 + 0));
      s1 += wts[1] * (*(const f32x4*)(x0 + 4));
      s0 += wts[2] * (*(const f32x4*)(x0 + 2160));
      s1 += wts[2] * (*(const f32x4*)(x0 + 2164));
      s0 += wts[3] * (*(const f32x4*)(x0 + 1044));
      s1 += wts[3] * (*(const f32x4*)(x0 + 1048));
      s0 += wts[4] * (*(const f32x4*)(x0 + 1116));
      s1 += wts[4] * (*(const f32x4*)(x0 + 1120));
#pragma unroll
      for (int j = 0; j < 4; ++j) {
        _Float16 h0 = (_Float16)s0[j];
        Ahi[j] = h0;
        Alo[j] = (_Float16)(s0[j] - (float)h0);
        _Float16 h1 = (_Float16)s1[j];
        Ahi[4 + j] = h1;
        Alo[4 + j] = (_Float16)(s1[j] - (float)h1);
      }
    }
    // ---- B fragments + MFMA (stride-40 rows -> single b128, conflict-free)
    const int kb = q * 8;
#pragma unroll
    for (int nt = 0; nt < 8; ++nt) {
      int n = nt * 16 + l16;
      half8 bhi = *(const half8*)(WThi + n * 40 + kb);
      half8 blo = *(const half8*)(WTlo + n * 40 + kb);
      acc[nt] = __builtin_amdgcn_mfma_f32_16x16x32_f16(Alo, bhi, acc[nt], 0, 0, 0);
      acc[nt] = __builtin_amdgcn_mfma_f32_16x16x32_f16(Ahi, blo, acc[nt], 0, 0, 0);
      acc[nt] = __builtin_amdgcn_mfma_f32_16x16x32_f16(Ahi, bhi, acc[nt], 0, 0, 0);
    }
  }

  // ---- epilogue: bias + LN + relu + residual, direct store from C/D layout
  float bgv[8], gv[8], btv[8];
#pragma unroll
  for (int nt = 0; nt < 8; ++nt) {
    int cl = nt * 16 + l16;
    bgv[nt] = bgp[cl];
    gv[nt] = gamp[cl];
    btv[nt] = betp[cl];
  }
#pragma unroll
  for (int reg = 0; reg < 4; ++reg) {
    float rs = 0.f;
#pragma unroll
    for (int nt = 0; nt < 8; ++nt) {
      acc[nt][reg] += bgv[nt];
      rs += acc[nt][reg];
    }
    rs += __shfl_xor(rs, 1, 64);
    rs += __shfl_xor(rs, 2, 64);
    rs += __shfl_xor(rs, 4, 64);
    rs += __shfl_xor(rs, 8, 64);
    float mean = rs * (1.f / 128.f);
    float ss = 0.f;
#pragma unroll
    for (int nt = 0; nt < 8; ++nt) {
      float d = acc[nt][reg] - mean;
      ss += d * d;
    }
    ss += __shfl_xor(ss, 1, 64);
    ss += __shfl_xor(ss, 2, 64);
    ss += __shfl_xor(ss, 4, 64);
    ss += __shfl_xor(ss, 8, 64);
    float rsd = rsqrtf(ss * (1.f / 128.f) + 1e-5f);
    int row = waveRow0 + q * 4 + reg;  // uniform across the 16-lane group
    if (row < nodesTotal) {
      const float* xr = Xin + (size_t)row * HID;
      float* xo = Xout + (size_t)row * HID;
#pragma unroll
      for (int nt = 0; nt < 8; ++nt) {
        int col = nt * 16 + l16;
        float y = fmaxf((acc[nt][reg] - mean) * rsd * gv[nt] + btv[nt], 0.f);
        xo[col] = y + xr[col];
      }
    }
  }
}

// ---------------------------------------------------------------------------
// Head v8: Out = Xin @ Wout + bout (v3-round2 verified structure, stride-40
// lo plane so blo is a single b128)
// ---------------------------------------------------------------------------
__global__ __launch_bounds__(512, 6) void k_head(
    const float* __restrict__ Xin, float* __restrict__ Out,
    const _Float16* __restrict__ Whi, const _Float16* __restrict__ Wlo,
    const float* __restrict__ bp, int nodesTotal) {
  constexpr int XTS = 36;
  __shared__ __attribute__((aligned(16))) float Xt[256 * XTS];     // 36864 B
  __shared__ __attribute__((aligned(16))) _Float16 WThi[64 * 40];  //  5120 B
  __shared__ __attribute__((aligned(16))) _Float16 WTlo[64 * 40];  //  5120 B

  const int t = threadIdx.x;
  const int lane = t & 63;
  const int wave = t >> 6;
  const int q = lane >> 4, l16 = lane & 15;
  const int blockRow0 = blockIdx.x * 256;
  const int waveRow0 = blockRow0 + wave * 32;

  int roff[2];
#pragma unroll
  for (int mt = 0; mt < 2; ++mt) {
    int nd = waveRow0 + mt * 16 + l16;
    if (nd > nodesTotal - 1) nd = nodesTotal - 1;
    roff[mt] = (nd - blockRow0) * XTS;
  }

  f32x4 acc[2][4];
#pragma unroll
  for (int mt = 0; mt < 2; ++mt)
#pragma unroll
    for (int nt = 0; nt < 4; ++nt) acc[mt][nt] = (f32x4){0.f, 0.f, 0.f, 0.f};

  for (int kc = 0; kc < 4; ++kc) {
    __syncthreads();
    for (int f = t; f < 256 * 8; f += 512) {
      int row = f >> 3, v = f & 7;
      int gr = blockRow0 + row;
      if (gr > nodesTotal - 1) gr = nodesTotal - 1;
      *(f32x4*)(Xt + row * XTS + v * 4) =
          *(const f32x4*)(Xin + (size_t)gr * HID + kc * 32 + v * 4);
    }
    {
      const f32x4* hs = (const f32x4*)(Whi + kc * 2560);
      if (t < 320) ((f32x4*)WThi)[t] = hs[t];
      const f32x4* ls = (const f32x4*)(Wlo + kc * 2560);
      if (t < 320) ((f32x4*)WTlo)[t] = ls[t];
    }
    __syncthreads();

    half8 Ahi[2], Alo[2];
#pragma unroll
    for (int mt = 0; mt < 2; ++mt) {
      const float* xp = Xt + roff[mt] + q * 8;
      f32x4 s0 = *(const f32x4*)xp;
      f32x4 s1 = *(const f32x4*)(xp + 4);
#pragma unroll
      for (int j = 0; j < 4; ++j) {
        _Float16 h0 = (_Float16)s0[j];
        Ahi[mt][j] = h0;
        Alo[mt][j] = (_Float16)(s0[j] - (float)h0);
        _Float16 h1 = (_Float16)s1[j];
        Ahi[mt][4 + j] = h1;
        Alo[mt][4 + j] = (_Float16)(s1[j] - (float)h1);
      }
    }
    const int kb = q * 8;
#pragma unroll
    for (int nt = 0; nt < 4; ++nt) {
      int n = nt * 16 + l16;
      half8 bhi = *(const half8*)(WThi + n * 40 + kb);
      half8 blo = *(const half8*)(WTlo + n * 40 + kb);
#pragma unroll
      for (int mt = 0; mt < 2; ++mt) {
        acc[mt][nt] = __builtin_amdgcn_mfma_f32_16x16x32_f16(Alo[mt], bhi, acc[mt][nt], 0, 0, 0);
        acc[mt][nt] = __builtin_amdgcn_mfma_f32_16x16x32_f16(Ahi[mt], blo, acc[mt][nt], 0, 0, 0);
        acc[mt][nt] = __builtin_amdgcn_mfma_f32_16x16x32_f16(Ahi[mt], bhi, acc[mt][nt], 0, 0, 0);
      }
    }
  }

  float bv[4];
#pragma unroll
  for (int nt = 0; nt < 4; ++nt) bv[nt] = bp[nt * 16 + l16];
#pragma unroll
  for (int mt = 0; mt < 2; ++mt) {
#pragma unroll
    for (int reg = 0; reg < 4; ++reg) {
      int row = waveRow0 + mt * 16 + q * 4 + reg;
      if (row < nodesTotal) {
        float* op = Out + (size_t)row * ODIM;
#pragma unroll
        for (int nt = 0; nt < 4; ++nt)
          op[nt * 16 + l16] = acc[mt][nt][reg] + bv[nt];
      }
    }
  }
}

// ---------------------------------------------------------------------------
extern "C" void kernel_launch(void* const* d_in, const int* in_sizes, int n_in,
                              void* d_out, int out_size, void* d_ws, size_t ws_size,
                              hipStream_t stream) {
  const int* grids = (const int*)d_in[0];
  // d_in[1] = edge_index: unused (fixed 30x30 grid + self-loops, analytic coefs)
  const float* Win  = (const float*)d_in[2];
  const float* bin  = (const float*)d_in[3];
  const float* Wg   = (const float*)d_in[4];
  const float* bg   = (const float*)d_in[5];
  const float* gam  = (const float*)d_in[6];
  const float* bet  = (const float*)d_in[7];
  const float* Wout = (const float*)d_in[8];
  const float* bout = (const float*)d_in[9];
  float* Out = (float*)d_out;

  // workspace: [pre-split W (368640 B) | Xa | Xb]
  _Float16* WspHi = (_Float16*)d_ws;
  _Float16* WspLo = WspHi + 81920;
  _Float16* WhHi  = WspHi + 163840;
  _Float16* WhLo  = WspHi + 174080;
  const size_t wBytes = 368640;

  const int Btot = 512;
  const size_t perBatchBytes = (size_t)900 * HID * 4 * 2;  // ping-pong X buffers
  size_t xws = ws_size > wBytes ? ws_size - wBytes : 0;
  int chunkB = (int)(xws / perBatchBytes);
  if (chunkB > Btot) chunkB = Btot;
  if (chunkB < 1) chunkB = 1;
  int nch = (Btot + chunkB - 1) / chunkB;

  float* Xa = (float*)((char*)d_ws + wBytes);
  float* Xb = Xa + (size_t)chunkB * 900 * HID;

  k_prep<<<dim3(720), dim3(256), 0, stream>>>(Wg, Wout, WspHi, WspLo, WhHi, WhLo);

  for (int ci = 0; ci < nch; ++ci) {
    int b0 = ci * chunkB;
    int cb = Btot - b0;
    if (cb > chunkB) cb = chunkB;
    int nodes = cb * 900;
    int gbh = (nodes + 127) / 128;   // k_hidden: M=128 tiles
    int gbo = (nodes + 255) / 256;   // k_head:   M=256 tiles

    k_encode<<<dim3((nodes * 32 + 255) / 256), dim3(256), 0, stream>>>(
        grids, Win, bin, Xa, b0, nodes);
    float* src = Xa;
    float* dst = Xb;
    for (int l = 0; l < 4; ++l) {
      k_hidden<<<dim3(gbh), dim3(512), 0, stream>>>(
          src, dst, WspHi + l * 20480, WspLo + l * 20480,
          bg + l * HID, gam + l * HID, bet + l * HID, nodes);
      float* tmp = src; src = dst; dst = tmp;
    }
    // after 4 swaps the final X is back in Xa
    k_head<<<dim3(gbo), dim3(512), 0, stream>>>(
        src, Out + (size_t)b0 * 900 * ODIM, WhHi, WhLo, bout, nodes);
  }
}